// Round 9
// baseline (253.711 us; speedup 1.0000x reference)
//
#include <hip/hip_runtime.h>
#include <math.h>

#define BSZ    256
#define GRID_N 49
#define LSTMH  512
#define CNN_C  2048
#define PROJ   512
#define KAUG   2560               // [cnn k=0..2047 | lstm k=2048..2559]
#define M_TOT  12544              // 256*49
#define BK     64
#define KTILES (KAUG / BK)        // 40

// ---- fast-path geometry: 128x128 tile ----
#define MT2    128
#define NT2    128
#define NBLK2  ((M_TOT / MT2) * (PROJ / NT2)) // 98*4 = 392 = 8*49; all co-resident @2/CU

// ---- fallback geometry ----
#define MT     64
#define NT     128
#define NBLK   ((M_TOT / MT) * (PROJ / NT))   // 784

#define WBLK   640                            // 512*320 W chunks / 256

typedef short bf16x8 __attribute__((ext_vector_type(8)));
typedef float f32x4  __attribute__((ext_vector_type(4)));

static __device__ __forceinline__ unsigned short bf16_rne(float f) {
    unsigned int u = __float_as_uint(f);
    u = u + 0x7FFFu + ((u >> 16) & 1u);
    return (unsigned short)(u >> 16);
}
static __device__ __forceinline__ uint4 pack8f(const float* f) {
    uint4 o;
    o.x = (unsigned int)bf16_rne(f[0]) | ((unsigned int)bf16_rne(f[1]) << 16);
    o.y = (unsigned int)bf16_rne(f[2]) | ((unsigned int)bf16_rne(f[3]) << 16);
    o.z = (unsigned int)bf16_rne(f[4]) | ((unsigned int)bf16_rne(f[5]) << 16);
    o.w = (unsigned int)bf16_rne(f[6]) | ((unsigned int)bf16_rne(f[7]) << 16);
    return o;
}
static __device__ __forceinline__ float tanh_fast(float x) {
    float e = __expf(2.f * x);
    return 1.f - 2.f / (e + 1.f);
}
// async 16B global->LDS (wave-uniform LDS base + lane*16)
static __device__ __forceinline__ void glds16(const void* g, void* l) {
    __builtin_amdgcn_global_load_lds(
        (const __attribute__((address_space(1))) unsigned int*)g,
        (__attribute__((address_space(3))) unsigned int*)l, 16, 0, 0);
}

// ==== prep: W_aug (512 x 2560) fp32 -> bf16(RNE); blocks 0..48 also zero out ====
// (round-3/4 verified kernel; ~11 MB streamed, ~4 us). wsA/wsL are GONE: the
// 160 MB cnn/lstm conversion pass (59.6 us measured, latency-bound at 1.8 TB/s)
// is fused into gemm9's pipeline instead.
__global__ __launch_bounds__(256) void prep_w(const float* __restrict__ Wc,
                                              const float* __restrict__ Wl,
                                              unsigned short* __restrict__ wsW,
                                              float* __restrict__ out) {
    const int bid = blockIdx.x, t = threadIdx.x;
    if (bid < 49) out[bid * 256 + t] = 0.f;     // 49*256 = 12544 exactly
    int c  = bid * 256 + t;
    int p  = c / 320;
    int kc = (c % 320) * 8;
    const float* src = (kc < CNN_C) ? (Wc + (size_t)p * CNN_C + kc)
                                    : (Wl + (size_t)p * LSTMH + (kc - CNN_C));
    float f[8];
    *(float4*)&f[0] = ((const float4*)src)[0];
    *(float4*)&f[4] = ((const float4*)src)[1];
    *(uint4*)(wsW + (size_t)p * KAUG + kc) = pack8f(f);
}

// ==== fast-path GEMM: counted-vmcnt 2-ahead pipeline + fused A conversion ====
// gemm8's schedule (vmcnt never drains to 0 until the last tile) with A
// reg-staged from fp32 cnn/lstm (T14): iter kt packs A(kt+1) (loads issued a
// full iteration earlier -> compiler's wait is the counted vmcnt(4)), issues
// A(kt+2) loads, computes tile kt, then stages B(kt+2) via glds. Top-of-iter
// wait = vmcnt(12) (A(kt+1) 8 loads + B(kt+1) 4 glds in flight). Pack uses
// v_cvt_pk_bf16_f32 (RNE): 16 VALU/tile/thread vs ~140 for bit-twiddle —
// round 3's hidden VALU cost.
__global__ __launch_bounds__(256, 2) void gemm9(
    const float* __restrict__ lstm, const float* __restrict__ cnn,
    const unsigned short* __restrict__ wsW,
    const float* __restrict__ bl, const float* __restrict__ bc,
    const float* __restrict__ wat, float* __restrict__ out)
{
    __shared__ unsigned short Ab[2][MT2][BK];   // 32 KB
    __shared__ unsigned short Bb[2][NT2][BK];   // 32 KB  (64 KB -> 2 blk/CU; 392 all fit)

    const int t   = threadIdx.x;
    const int w   = t >> 6;
    const int l   = t & 63;
    const int q   = l >> 4;
    const int r16 = l & 15;
    const int wr  = w >> 1;          // wave grid 2x2, wave owns 64x64
    const int wc  = w & 1;

    // XCD-bijective swizzle: 392 = 8*49; 4 n-blocks of one m-panel stay adjacent.
    const int bid = (int)blockIdx.x;
    const int swz = (bid & 7) * (NBLK2 / 8) + (bid >> 3);
    const int m0  = (swz >> 2) * MT2;
    const int n0  = (swz & 3) * NT2;

    // B glds lane geometry: 8 rows x 8 chunks (16B); read-swizzle folded into
    // SOURCE chunk (LDS dest stays linear: rule 21).
    const int srow = l >> 3;
    const int cg   = (l & 7) ^ srow;

    // A reg-staging identity (round-3 proven): thread owns row ar = t>>1,
    // chunks ac0..ac0+3 (8 floats each); XOR-swizzled ds_write.
    const int ar  = t >> 1;
    const int ac0 = (t & 1) * 4;
    const int sw  = ar & 7;
    const int grow = m0 + ar;
    const int ab_  = grow / 49;
    const int ag_  = grow - ab_ * 49;
    const float* cnnb  = cnn + ((size_t)ab_ * GRID_N + ag_) * CNN_C;
    const float* lstmb = lstm + (size_t)ab_ * LSTMH;

    float4 fa[8];                              // A fp32 prefetch (32 floats)
    auto a_load = [&](int kt) {
        const int k0 = kt * BK;
        const float* s = (((k0 < CNN_C) ? (cnnb + k0) : (lstmb + (k0 - CNN_C)))) + ac0 * 8;
        #pragma unroll
        for (int i = 0; i < 8; ++i) fa[i] = ((const float4*)s)[i];
    };
    auto a_pack_write = [&](int bufi) {        // v_cvt_pk_bf16_f32: 2 f32 -> 1 dword
        #pragma unroll
        for (int c = 0; c < 4; ++c) {
            const float4 x = fa[2 * c], y = fa[2 * c + 1];
            uint4 o;
            asm("v_cvt_pk_bf16_f32 %0, %1, %2" : "=v"(o.x) : "v"(x.x), "v"(x.y));
            asm("v_cvt_pk_bf16_f32 %0, %1, %2" : "=v"(o.y) : "v"(x.z), "v"(x.w));
            asm("v_cvt_pk_bf16_f32 %0, %1, %2" : "=v"(o.z) : "v"(y.x), "v"(y.y));
            asm("v_cvt_pk_bf16_f32 %0, %1, %2" : "=v"(o.w) : "v"(y.z), "v"(y.w));
            *(uint4*)&Ab[bufi][ar][((ac0 + c) ^ sw) * 8] = o;
        }
    };
    auto b_stage = [&](int kt, int bufi) {     // exactly 4 glds/wave
        const int k0 = kt * BK;
        #pragma unroll
        for (int j = 0; j < 4; ++j) {
            const int rowb = w * 32 + j * 8;
            const unsigned short* g = wsW + (size_t)(n0 + rowb + srow) * KAUG + k0 + cg * 8;
            glds16(g, &Bb[bufi][rowb][0]);
        }
    };

    f32x4 acc[4][4];
    #pragma unroll
    for (int mt = 0; mt < 4; ++mt)
        #pragma unroll
        for (int nt = 0; nt < 4; ++nt)
            acc[mt][nt] = (f32x4){0.f, 0.f, 0.f, 0.f};

    // prologue: FIFO = [A0(8), B0(4)] -> pack A0 (compiler waits vmcnt(4)) ->
    // [B0, A1(8), B1(4)]; iter-0's top vmcnt(12) drains B0 exactly.
    a_load(0);
    b_stage(0, 0);
    a_pack_write(0);
    a_load(1);
    b_stage(1, 1);
    asm volatile("s_waitcnt lgkmcnt(0)" ::: "memory");   // A0 ds_writes issued & done

    for (int kt = 0; kt < KTILES; ++kt) {
        const int cur = kt & 1;
        // B(kt) complete; A(kt+1)+B(kt+1) = 12 may stay outstanding.
        if (kt + 1 < KTILES) {
            asm volatile("s_waitcnt vmcnt(12)" ::: "memory");
        } else {
            asm volatile("s_waitcnt vmcnt(0)" ::: "memory");
        }
        __builtin_amdgcn_s_barrier();          // tile kt (A in LDS since kt-1; B now) ready
        if (kt + 1 < KTILES) a_pack_write(cur ^ 1);  // A(kt+1): reg->bf16->LDS
        if (kt + 2 < KTILES) a_load(kt + 2);         // 8 fp32 loads, 1-iter lead
        __builtin_amdgcn_sched_barrier(0);           // keep loads above compute
        #pragma unroll
        for (int ks = 0; ks < 2; ++ks) {
            const int cp = ((ks * 4 + q) ^ (r16 & 7)) * 8;
            bf16x8 af[4], bfr[4];
            #pragma unroll
            for (int mt = 0; mt < 4; ++mt)
                af[mt] = *(const bf16x8*)&Ab[cur][wr * 64 + mt * 16 + r16][cp];
            #pragma unroll
            for (int nt = 0; nt < 4; ++nt)
                bfr[nt] = *(const bf16x8*)&Bb[cur][wc * 64 + nt * 16 + r16][cp];
            #pragma unroll
            for (int mt = 0; mt < 4; ++mt)
                #pragma unroll
                for (int nt = 0; nt < 4; ++nt)
                    acc[mt][nt] = __builtin_amdgcn_mfma_f32_16x16x32_bf16(
                        af[mt], bfr[nt], acc[mt][nt], 0, 0, 0);
        }
        asm volatile("s_waitcnt lgkmcnt(0)" ::: "memory");  // A(kt+1) writes visible
        __builtin_amdgcn_s_barrier();          // all reads of buf[cur] done
        if (kt + 2 < KTILES) b_stage(kt + 2, cur);   // refill B buffer just consumed
    }

    // ---- epilogue: tanh + w_attn partial dot over this block's 128 cols ----
    float* zpf = (float*)&Ab[0][0][0];        // reuse LDS (tiles dead)
    float part[4][4];
    #pragma unroll
    for (int mt = 0; mt < 4; ++mt)
        #pragma unroll
        for (int rr = 0; rr < 4; ++rr) part[mt][rr] = 0.f;
    #pragma unroll
    for (int nt = 0; nt < 4; ++nt) {
        const int p = n0 + wc * 64 + nt * 16 + r16;
        const float bb = bl[p] + bc[p];
        const float wa = wat[p];
        #pragma unroll
        for (int mt = 0; mt < 4; ++mt)
            #pragma unroll
            for (int rr = 0; rr < 4; ++rr)
                part[mt][rr] += tanh_fast(acc[mt][nt][rr] + bb) * wa;
    }
    #pragma unroll
    for (int mt = 0; mt < 4; ++mt)
        #pragma unroll
        for (int rr = 0; rr < 4; ++rr) {
            float v = part[mt][rr];
            v += __shfl_xor(v, 1);
            v += __shfl_xor(v, 2);
            v += __shfl_xor(v, 4);
            v += __shfl_xor(v, 8);            // sum over 16 cols (r16 group)
            if (r16 == 0) zpf[wc * MT2 + wr * 64 + mt * 16 + q * 4 + rr] = v;
        }
    __syncthreads();
    if (t < MT2) {
        const float v = zpf[t] + zpf[MT2 + t];
        const int row = m0 + t;
        const int b2  = row / 49;
        const int g2  = row - b2 * 49;
        atomicAdd(&out[g2 * BSZ + b2], v);    // scrambled position
    }
}

// ==== fallback (no workspace): verified convert-in-kernel GEMM ====
__global__ __launch_bounds__(256, 4) void gemm_k(
    const float* __restrict__ lstm, const float* __restrict__ cnn,
    const float* __restrict__ Wc,   const float* __restrict__ Wl,
    const float* __restrict__ bl,   const float* __restrict__ bc,
    const float* __restrict__ wat,  float* __restrict__ out)
{
    __shared__ unsigned short Ash[MT][BK];
    __shared__ unsigned short Bsh[NT][BK];
    __shared__ float zp[4][MT];

    const int t   = threadIdx.x;
    const int w   = t >> 6;
    const int l   = t & 63;
    const int q   = l >> 4;
    const int r16 = l & 15;

    const int bid = (int)blockIdx.x;
    const int swz = (bid & 7) * (NBLK / 8) + (bid >> 3);
    const int m0 = (swz >> 2) * MT;
    const int n0 = (swz & 3) * NT;

    const int ra  = t >> 2;
    const int ca0 = t & 3;
    const int sa  = ra & 7;
    const int grow = m0 + ra;
    const int ab   = grow / 49;
    const int ag   = grow - ab * 49;
    const float* cnnb  = cnn + ((size_t)ab * GRID_N + ag) * CNN_C;
    const float* lstmb = lstm + (size_t)ab * LSTMH;

    f32x4 acc[4][2];
    #pragma unroll
    for (int mt = 0; mt < 4; ++mt)
        #pragma unroll
        for (int nt = 0; nt < 2; ++nt)
            acc[mt][nt] = (f32x4){0.f, 0.f, 0.f, 0.f};

    float4 fa0, fa1, fa2, fa3;

    auto a_load = [&](int k0) {
        const float* s = (k0 < CNN_C) ? (cnnb + k0) : (lstmb + (k0 - CNN_C));
        const float4* p0 = (const float4*)(s + ca0 * 8);
        const float4* p1 = (const float4*)(s + (ca0 + 4) * 8);
        fa0 = p0[0]; fa1 = p0[1];
        fa2 = p1[0]; fa3 = p1[1];
    };
    auto a_write = [&]() {
        float f[8];
        *(float4*)&f[0] = fa0; *(float4*)&f[4] = fa1;
        *(uint4*)&Ash[ra][(ca0 ^ sa) * 8] = pack8f(f);
        *(float4*)&f[0] = fa2; *(float4*)&f[4] = fa3;
        *(uint4*)&Ash[ra][((ca0 + 4) ^ sa) * 8] = pack8f(f);
    };
    auto b_stage = [&](int k0) {
        const int rb = t >> 1;
        const int hb = t & 1;
        const float* s = (k0 < CNN_C) ? (Wc + (size_t)(n0 + rb) * CNN_C + k0)
                                      : (Wl + (size_t)(n0 + rb) * LSTMH + (k0 - CNN_C));
        const int sw = rb & 7;
        #pragma unroll
        for (int c = 0; c < 4; ++c) {
            const int cc = hb * 4 + c;
            float f[8];
            *(float4*)&f[0] = ((const float4*)(s + cc * 8))[0];
            *(float4*)&f[4] = ((const float4*)(s + cc * 8))[1];
            *(uint4*)&Bsh[rb][(cc ^ sw) * 8] = pack8f(f);
        }
    };

    a_load(0);
    a_write();
    b_stage(0);

    for (int kt = 0; kt < KTILES; ++kt) {
        __syncthreads();
        const bool more = (kt + 1 < KTILES);
        if (more) a_load((kt + 1) * BK);
        #pragma unroll
        for (int ks = 0; ks < 2; ++ks) {
            const int cp = ((ks * 4 + q) ^ (r16 & 7)) * 8;
            bf16x8 af[4], bfr[2];
            #pragma unroll
            for (int mt = 0; mt < 4; ++mt)
                af[mt] = *(const bf16x8*)&Ash[mt * 16 + r16][cp];
            #pragma unroll
            for (int nt = 0; nt < 2; ++nt)
                bfr[nt] = *(const bf16x8*)&Bsh[w * 32 + nt * 16 + r16][cp];
            #pragma unroll
            for (int mt = 0; mt < 4; ++mt)
                #pragma unroll
                for (int nt = 0; nt < 2; ++nt)
                    acc[mt][nt] = __builtin_amdgcn_mfma_f32_16x16x32_bf16(
                        af[mt], bfr[nt], acc[mt][nt], 0, 0, 0);
        }
        __syncthreads();
        if (more) { a_write(); b_stage((kt + 1) * BK); }
    }

    float part[4][4];
    #pragma unroll
    for (int mt = 0; mt < 4; ++mt)
        #pragma unroll
        for (int rr = 0; rr < 4; ++rr) part[mt][rr] = 0.f;
    #pragma unroll
    for (int nt = 0; nt < 2; ++nt) {
        const int p = n0 + w * 32 + nt * 16 + r16;
        const float bb = bl[p] + bc[p];
        const float wa = wat[p];
        #pragma unroll
        for (int mt = 0; mt < 4; ++mt)
            #pragma unroll
            for (int rr = 0; rr < 4; ++rr)
                part[mt][rr] += tanh_fast(acc[mt][nt][rr] + bb) * wa;
    }
    #pragma unroll
    for (int mt = 0; mt < 4; ++mt)
        #pragma unroll
        for (int rr = 0; rr < 4; ++rr) {
            float v = part[mt][rr];
            v += __shfl_xor(v, 1);
            v += __shfl_xor(v, 2);
            v += __shfl_xor(v, 4);
            v += __shfl_xor(v, 8);
            if (r16 == 0) zp[w][mt * 16 + q * 4 + rr] = v;
        }
    __syncthreads();
    if (t < MT) {
        const float v = zp[0][t] + zp[1][t] + zp[2][t] + zp[3][t];
        const int row = m0 + t;
        const int b2  = row / 49;
        const int g2  = row - b2 * 49;
        atomicAdd(&out[g2 * BSZ + b2], v);
    }
}

// Row softmax over 49 elements, in place. One wave per row.
__global__ __launch_bounds__(64) void softmax_rows(float* __restrict__ out)
{
    const int i = blockIdx.x;
    const int j = threadIdx.x;
    float x = (j < GRID_N) ? out[i * GRID_N + j] : -1e30f;
    float m = x;
    #pragma unroll
    for (int off = 32; off > 0; off >>= 1) m = fmaxf(m, __shfl_xor(m, off));
    float e = (j < GRID_N) ? __expf(x - m) : 0.f;
    float s = e;
    #pragma unroll
    for (int off = 32; off > 0; off >>= 1) s += __shfl_xor(s, off);
    if (j < GRID_N) out[i * GRID_N + j] = e / s;
}

extern "C" void kernel_launch(void* const* d_in, const int* in_sizes, int n_in,
                              void* d_out, int out_size, void* d_ws, size_t ws_size,
                              hipStream_t stream)
{
    const float* lstm = (const float*)d_in[0];
    const float* cnn  = (const float*)d_in[1];
    const float* Wl   = (const float*)d_in[2];
    const float* bl   = (const float*)d_in[3];
    const float* Wc   = (const float*)d_in[4];
    const float* bc   = (const float*)d_in[5];
    const float* wat  = (const float*)d_in[6];
    float* out = (float*)d_out;

    const size_t szW = (size_t)PROJ * KAUG * sizeof(unsigned short);    // 2.62 MB

    if (ws_size >= szW) {
        unsigned short* wsW = (unsigned short*)d_ws;
        prep_w<<<dim3(WBLK), dim3(256), 0, stream>>>(Wc, Wl, wsW, out);
        gemm9<<<dim3(NBLK2), dim3(256), 0, stream>>>(lstm, cnn, wsW, bl, bc, wat, out);
    } else {
        hipMemsetAsync(out, 0, (size_t)out_size * sizeof(float), stream);
        gemm_k<<<dim3(NBLK), dim3(256), 0, stream>>>(lstm, cnn, Wc, Wl, bl, bc, wat, out);
    }
    softmax_rows<<<dim3(BSZ), dim3(64), 0, stream>>>(out);
}

// Round 10
// 212.346 us; speedup vs baseline: 1.1948x; 1.1948x over previous
//
#include <hip/hip_runtime.h>
#include <math.h>

#define BSZ    256
#define GRID_N 49
#define LSTMH  512
#define CNN_C  2048
#define PROJ   512
#define KAUG   2560               // [cnn k=0..2047 | lstm k=2048..2559]
#define M_TOT  12544              // 256*49
#define BK     64
#define KTILES (KAUG / BK)        // 40

// ---- fast-path geometry: 128x128 tile ----
#define MT2    128
#define NT2    128
#define NBLK2  ((M_TOT / MT2) * (PROJ / NT2)) // 98*4 = 392 = 8*49; all co-resident @2/CU

// ---- fallback geometry ----
#define MT     64
#define NT     128
#define NBLK   ((M_TOT / MT) * (PROJ / NT))   // 784

// ---- prep grid (round-2 verified one-shot layout) ----
#define ACHUNKS (M_TOT * CNN_C / 8)           // 3,211,264 cnn 8-float chunks
#define LCHUNKS (BSZ * LSTMH / 8)             // 16,384 lstm chunks
#define ABLK    ((ACHUNKS + LCHUNKS) / 256)   // 12,608
#define WBLK    640                           // 512*320 W chunks / 256
#define PBLK    (ABLK + WBLK)                 // 13,248

typedef short bf16x8 __attribute__((ext_vector_type(8)));
typedef float f32x4  __attribute__((ext_vector_type(4)));

static __device__ __forceinline__ unsigned short bf16_rne(float f) {
    unsigned int u = __float_as_uint(f);
    u = u + 0x7FFFu + ((u >> 16) & 1u);
    return (unsigned short)(u >> 16);
}
static __device__ __forceinline__ uint4 pack8f(const float* f) {
    uint4 o;
    o.x = (unsigned int)bf16_rne(f[0]) | ((unsigned int)bf16_rne(f[1]) << 16);
    o.y = (unsigned int)bf16_rne(f[2]) | ((unsigned int)bf16_rne(f[3]) << 16);
    o.z = (unsigned int)bf16_rne(f[4]) | ((unsigned int)bf16_rne(f[5]) << 16);
    o.w = (unsigned int)bf16_rne(f[6]) | ((unsigned int)bf16_rne(f[7]) << 16);
    return o;
}
static __device__ __forceinline__ float tanh_fast(float x) {
    float e = __expf(2.f * x);
    return 1.f - 2.f / (e + 1.f);
}
// async 16B global->LDS (wave-uniform LDS base + lane*16)
static __device__ __forceinline__ void glds16(const void* g, void* l) {
    __builtin_amdgcn_global_load_lds(
        (const __attribute__((address_space(1))) unsigned int*)g,
        (__attribute__((address_space(3))) unsigned int*)l, 16, 0, 0);
}

// ==== prep: zero out + convert W_aug, cnn, lstm to bf16 (ONE-SHOT, round-2) ====
// Measured ~34 us (never in top-5, cutoff ~59). The grid-stride variants
// (prep_all2/3) regressed monotonically 34->44->59.6 us -- one-shot micro-
// blocks are the right shape for this op. Do not "improve" this again without
// PMC evidence.
__global__ __launch_bounds__(256) void prep_all(
    const float* __restrict__ cnn, const float* __restrict__ lstm,
    const float* __restrict__ Wc,  const float* __restrict__ Wl,
    unsigned short* __restrict__ wsW, unsigned short* __restrict__ wsA,
    unsigned short* __restrict__ wsL, float* __restrict__ out)
{
    const int bid = blockIdx.x, t = threadIdx.x;
    if (bid < 49) out[bid * 256 + t] = 0.f;     // 49*256 = 12544 exactly
    float f[8];
    if (bid < ABLK) {                           // cnn / lstm: pure linear convert
        const int c = bid * 256 + t;
        const float* src; unsigned short* dst;
        if (c < ACHUNKS) { src = cnn  + (size_t)c * 8; dst = wsA + (size_t)c * 8; }
        else { const int c2 = c - ACHUNKS; src = lstm + (size_t)c2 * 8; dst = wsL + (size_t)c2 * 8; }
        *(float4*)&f[0] = ((const float4*)src)[0];
        *(float4*)&f[4] = ((const float4*)src)[1];
        *(uint4*)dst = pack8f(f);
    } else {                                    // W_aug layout [512][2560]
        const int c  = (bid - ABLK) * 256 + t;
        const int p  = c / 320;
        const int kc = (c % 320) * 8;
        const float* src = (kc < CNN_C) ? (Wc + (size_t)p * CNN_C + kc)
                                        : (Wl + (size_t)p * LSTMH + (kc - CNN_C));
        *(float4*)&f[0] = ((const float4*)src)[0];
        *(float4*)&f[4] = ((const float4*)src)[1];
        *(uint4*)(wsW + (size_t)p * KAUG + kc) = pack8f(f);
    }
}

// ==== fast-path GEMM: counted-vmcnt 2-tiles-ahead pipeline (round-8 verified) ====
// Tile k's 8 glds issued at the END of iter k-2; top-of-iter wait is vmcnt(8)
// (tile k complete, tile k+1's 8 loads stay in flight). The glds queue never
// empties until the final iteration. Measured ~40 us (below top-5 cutoff),
// vs ~60 us for every drain-to-zero variant (gemm2/4/5/6) and 78 us for the
// 48 KB 3-block variant (gemm7).
__global__ __launch_bounds__(256, 2) void gemm8(
    const unsigned short* __restrict__ wsW, const unsigned short* __restrict__ wsA,
    const unsigned short* __restrict__ wsL,
    const float* __restrict__ bl, const float* __restrict__ bc,
    const float* __restrict__ wat, float* __restrict__ out)
{
    __shared__ unsigned short Ab[2][MT2][BK];   // 32 KB
    __shared__ unsigned short Bb[2][NT2][BK];   // 32 KB  (64 KB -> 2 blk/CU; 392 all fit)

    const int t   = threadIdx.x;
    const int w   = t >> 6;
    const int l   = t & 63;
    const int q   = l >> 4;
    const int r16 = l & 15;
    const int wr  = w >> 1;          // wave grid 2x2, wave owns 64x64
    const int wc  = w & 1;

    // XCD-bijective swizzle: 392 = 8*49; 4 n-blocks of one m-panel stay adjacent.
    const int bid = (int)blockIdx.x;
    const int swz = (bid & 7) * (NBLK2 / 8) + (bid >> 3);
    const int m0  = (swz >> 2) * MT2;
    const int n0  = (swz & 3) * NT2;

    // glds lane geometry: one instr = 8 rows x 8 chunks (16B); read-swizzle
    // folded into SOURCE chunk (LDS dest stays linear: rule 21).
    const int srow = l >> 3;
    const int cg   = (l & 7) ^ srow;

    // stage = exactly 8 glds/wave (4 B + 4 A) -- uniform count for vmcnt math
    auto stage = [&](int kt, int bufi) {
        const int k0 = kt * BK;
        #pragma unroll
        for (int j = 0; j < 4; ++j) {
            const int rowb = w * 32 + j * 8;
            const unsigned short* g = wsW + (size_t)(n0 + rowb + srow) * KAUG + k0 + cg * 8;
            glds16(g, &Bb[bufi][rowb][0]);
        }
        if (k0 < CNN_C) {                     // tiles 0..31 (2048/64=32 exact)
            #pragma unroll
            for (int j = 0; j < 4; ++j) {
                const int rowa = w * 32 + j * 8;
                const unsigned short* g = wsA + (size_t)(m0 + rowa + srow) * CNN_C + k0 + cg * 8;
                glds16(g, &Ab[bufi][rowa][0]);
            }
        } else {                              // lstm bf16 (unreplicated), row -> b = row/49
            const int k0l = k0 - CNN_C;
            #pragma unroll
            for (int j = 0; j < 4; ++j) {
                const int rowa = w * 32 + j * 8;
                const int rg   = m0 + rowa + srow;
                const unsigned short* g = wsL + (size_t)(rg / 49) * LSTMH + k0l + cg * 8;
                glds16(g, &Ab[bufi][rowa][0]);
            }
        }
    };

    f32x4 acc[4][4];
    #pragma unroll
    for (int mt = 0; mt < 4; ++mt)
        #pragma unroll
        for (int nt = 0; nt < 4; ++nt)
            acc[mt][nt] = (f32x4){0.f, 0.f, 0.f, 0.f};

    // prologue: tiles 0 and 1 both in flight (16 glds outstanding)
    stage(0, 0);
    stage(1, 1);

    for (int kt = 0; kt < KTILES; ++kt) {
        const int cur = kt & 1;
        // wait: tile kt complete; tile kt+1's 8 loads may stay outstanding
        if (kt + 1 < KTILES) {
            asm volatile("s_waitcnt vmcnt(8)" ::: "memory");
        } else {
            asm volatile("s_waitcnt vmcnt(0)" ::: "memory");
        }
        __builtin_amdgcn_s_barrier();         // all waves confirm tile kt in LDS
        #pragma unroll
        for (int ks = 0; ks < 2; ++ks) {
            const int cp = ((ks * 4 + q) ^ (r16 & 7)) * 8;
            bf16x8 af[4], bfr[4];
            #pragma unroll
            for (int mt = 0; mt < 4; ++mt)
                af[mt] = *(const bf16x8*)&Ab[cur][wr * 64 + mt * 16 + r16][cp];
            #pragma unroll
            for (int nt = 0; nt < 4; ++nt)
                bfr[nt] = *(const bf16x8*)&Bb[cur][wc * 64 + nt * 16 + r16][cp];
            #pragma unroll
            for (int mt = 0; mt < 4; ++mt)
                #pragma unroll
                for (int nt = 0; nt < 4; ++nt)
                    acc[mt][nt] = __builtin_amdgcn_mfma_f32_16x16x32_bf16(
                        af[mt], bfr[nt], acc[mt][nt], 0, 0, 0);
        }
        __builtin_amdgcn_s_barrier();         // all waves' reads of buf[cur] done
        if (kt + 2 < KTILES) stage(kt + 2, cur);   // refill the buffer just consumed
    }

    // ---- epilogue: tanh + w_attn partial dot over this block's 128 cols ----
    float* zpf = (float*)&Ab[0][0][0];        // reuse LDS (tiles dead)
    float part[4][4];
    #pragma unroll
    for (int mt = 0; mt < 4; ++mt)
        #pragma unroll
        for (int rr = 0; rr < 4; ++rr) part[mt][rr] = 0.f;
    #pragma unroll
    for (int nt = 0; nt < 4; ++nt) {
        const int p = n0 + wc * 64 + nt * 16 + r16;
        const float bb = bl[p] + bc[p];
        const float wa = wat[p];
        #pragma unroll
        for (int mt = 0; mt < 4; ++mt)
            #pragma unroll
            for (int rr = 0; rr < 4; ++rr)
                part[mt][rr] += tanh_fast(acc[mt][nt][rr] + bb) * wa;
    }
    #pragma unroll
    for (int mt = 0; mt < 4; ++mt)
        #pragma unroll
        for (int rr = 0; rr < 4; ++rr) {
            float v = part[mt][rr];
            v += __shfl_xor(v, 1);
            v += __shfl_xor(v, 2);
            v += __shfl_xor(v, 4);
            v += __shfl_xor(v, 8);            // sum over 16 cols (r16 group)
            if (r16 == 0) zpf[wc * MT2 + wr * 64 + mt * 16 + q * 4 + rr] = v;
        }
    __syncthreads();
    if (t < MT2) {
        const float v = zpf[t] + zpf[MT2 + t];
        const int row = m0 + t;
        const int b2  = row / 49;
        const int g2  = row - b2 * 49;
        atomicAdd(&out[g2 * BSZ + b2], v);    // scrambled position
    }
}

// ==== fallback (no workspace): verified convert-in-kernel GEMM ====
__global__ __launch_bounds__(256, 4) void gemm_k(
    const float* __restrict__ lstm, const float* __restrict__ cnn,
    const float* __restrict__ Wc,   const float* __restrict__ Wl,
    const float* __restrict__ bl,   const float* __restrict__ bc,
    const float* __restrict__ wat,  float* __restrict__ out)
{
    __shared__ unsigned short Ash[MT][BK];
    __shared__ unsigned short Bsh[NT][BK];
    __shared__ float zp[4][MT];

    const int t   = threadIdx.x;
    const int w   = t >> 6;
    const int l   = t & 63;
    const int q   = l >> 4;
    const int r16 = l & 15;

    const int bid = (int)blockIdx.x;
    const int swz = (bid & 7) * (NBLK / 8) + (bid >> 3);
    const int m0 = (swz >> 2) * MT;
    const int n0 = (swz & 3) * NT;

    const int ra  = t >> 2;
    const int ca0 = t & 3;
    const int sa  = ra & 7;
    const int grow = m0 + ra;
    const int ab   = grow / 49;
    const int ag   = grow - ab * 49;
    const float* cnnb  = cnn + ((size_t)ab * GRID_N + ag) * CNN_C;
    const float* lstmb = lstm + (size_t)ab * LSTMH;

    f32x4 acc[4][2];
    #pragma unroll
    for (int mt = 0; mt < 4; ++mt)
        #pragma unroll
        for (int nt = 0; nt < 2; ++nt)
            acc[mt][nt] = (f32x4){0.f, 0.f, 0.f, 0.f};

    float4 fa0, fa1, fa2, fa3;

    auto a_load = [&](int k0) {
        const float* s = (k0 < CNN_C) ? (cnnb + k0) : (lstmb + (k0 - CNN_C));
        const float4* p0 = (const float4*)(s + ca0 * 8);
        const float4* p1 = (const float4*)(s + (ca0 + 4) * 8);
        fa0 = p0[0]; fa1 = p0[1];
        fa2 = p1[0]; fa3 = p1[1];
    };
    auto a_write = [&]() {
        float f[8];
        *(float4*)&f[0] = fa0; *(float4*)&f[4] = fa1;
        *(uint4*)&Ash[ra][(ca0 ^ sa) * 8] = pack8f(f);
        *(float4*)&f[0] = fa2; *(float4*)&f[4] = fa3;
        *(uint4*)&Ash[ra][((ca0 + 4) ^ sa) * 8] = pack8f(f);
    };
    auto b_stage = [&](int k0) {
        const int rb = t >> 1;
        const int hb = t & 1;
        const float* s = (k0 < CNN_C) ? (Wc + (size_t)(n0 + rb) * CNN_C + k0)
                                      : (Wl + (size_t)(n0 + rb) * LSTMH + (k0 - CNN_C));
        const int sw = rb & 7;
        #pragma unroll
        for (int c = 0; c < 4; ++c) {
            const int cc = hb * 4 + c;
            float f[8];
            *(float4*)&f[0] = ((const float4*)(s + cc * 8))[0];
            *(float4*)&f[4] = ((const float4*)(s + cc * 8))[1];
            *(uint4*)&Bsh[rb][(cc ^ sw) * 8] = pack8f(f);
        }
    };

    a_load(0);
    a_write();
    b_stage(0);

    for (int kt = 0; kt < KTILES; ++kt) {
        __syncthreads();
        const bool more = (kt + 1 < KTILES);
        if (more) a_load((kt + 1) * BK);
        #pragma unroll
        for (int ks = 0; ks < 2; ++ks) {
            const int cp = ((ks * 4 + q) ^ (r16 & 7)) * 8;
            bf16x8 af[4], bfr[2];
            #pragma unroll
            for (int mt = 0; mt < 4; ++mt)
                af[mt] = *(const bf16x8*)&Ash[mt * 16 + r16][cp];
            #pragma unroll
            for (int nt = 0; nt < 2; ++nt)
                bfr[nt] = *(const bf16x8*)&Bsh[w * 32 + nt * 16 + r16][cp];
            #pragma unroll
            for (int mt = 0; mt < 4; ++mt)
                #pragma unroll
                for (int nt = 0; nt < 2; ++nt)
                    acc[mt][nt] = __builtin_amdgcn_mfma_f32_16x16x32_bf16(
                        af[mt], bfr[nt], acc[mt][nt], 0, 0, 0);
        }
        __syncthreads();
        if (more) { a_write(); b_stage((kt + 1) * BK); }
    }

    float part[4][4];
    #pragma unroll
    for (int mt = 0; mt < 4; ++mt)
        #pragma unroll
        for (int rr = 0; rr < 4; ++rr) part[mt][rr] = 0.f;
    #pragma unroll
    for (int nt = 0; nt < 2; ++nt) {
        const int p = n0 + w * 32 + nt * 16 + r16;
        const float bb = bl[p] + bc[p];
        const float wa = wat[p];
        #pragma unroll
        for (int mt = 0; mt < 4; ++mt)
            #pragma unroll
            for (int rr = 0; rr < 4; ++rr)
                part[mt][rr] += tanh_fast(acc[mt][nt][rr] + bb) * wa;
    }
    #pragma unroll
    for (int mt = 0; mt < 4; ++mt)
        #pragma unroll
        for (int rr = 0; rr < 4; ++rr) {
            float v = part[mt][rr];
            v += __shfl_xor(v, 1);
            v += __shfl_xor(v, 2);
            v += __shfl_xor(v, 4);
            v += __shfl_xor(v, 8);
            if (r16 == 0) zp[w][mt * 16 + q * 4 + rr] = v;
        }
    __syncthreads();
    if (t < MT) {
        const float v = zp[0][t] + zp[1][t] + zp[2][t] + zp[3][t];
        const int row = m0 + t;
        const int b2  = row / 49;
        const int g2  = row - b2 * 49;
        atomicAdd(&out[g2 * BSZ + b2], v);
    }
}

// Row softmax over 49 elements, in place. One wave per row.
__global__ __launch_bounds__(64) void softmax_rows(float* __restrict__ out)
{
    const int i = blockIdx.x;
    const int j = threadIdx.x;
    float x = (j < GRID_N) ? out[i * GRID_N + j] : -1e30f;
    float m = x;
    #pragma unroll
    for (int off = 32; off > 0; off >>= 1) m = fmaxf(m, __shfl_xor(m, off));
    float e = (j < GRID_N) ? __expf(x - m) : 0.f;
    float s = e;
    #pragma unroll
    for (int off = 32; off > 0; off >>= 1) s += __shfl_xor(s, off);
    if (j < GRID_N) out[i * GRID_N + j] = e / s;
}

extern "C" void kernel_launch(void* const* d_in, const int* in_sizes, int n_in,
                              void* d_out, int out_size, void* d_ws, size_t ws_size,
                              hipStream_t stream)
{
    const float* lstm = (const float*)d_in[0];
    const float* cnn  = (const float*)d_in[1];
    const float* Wl   = (const float*)d_in[2];
    const float* bl   = (const float*)d_in[3];
    const float* Wc   = (const float*)d_in[4];
    const float* bc   = (const float*)d_in[5];
    const float* wat  = (const float*)d_in[6];
    float* out = (float*)d_out;

    const size_t szW = (size_t)PROJ * KAUG * sizeof(unsigned short);    // 2.62 MB
    const size_t szA = (size_t)M_TOT * CNN_C * sizeof(unsigned short);  // 51.4 MB
    const size_t szL = (size_t)BSZ * LSTMH * sizeof(unsigned short);    // 0.26 MB

    if (ws_size >= szW + szA + szL) {
        unsigned short* wsW = (unsigned short*)d_ws;
        unsigned short* wsA = wsW + (size_t)PROJ * KAUG;
        unsigned short* wsL = wsA + (size_t)M_TOT * CNN_C;
        prep_all<<<dim3(PBLK), dim3(256), 0, stream>>>(cnn, lstm, Wc, Wl, wsW, wsA, wsL, out);
        gemm8<<<dim3(NBLK2), dim3(256), 0, stream>>>(wsW, wsA, wsL, bl, bc, wat, out);
    } else {
        hipMemsetAsync(out, 0, (size_t)out_size * sizeof(float), stream);
        gemm_k<<<dim3(NBLK), dim3(256), 0, stream>>>(lstm, cnn, Wc, Wl, bl, bc, wat, out);
    }
    softmax_rows<<<dim3(BSZ), dim3(64), 0, stream>>>(out);
}